// Round 1
// baseline (177.394 us; speedup 1.0000x reference)
//
#include <hip/hip_runtime.h>
#include <hip/hip_fp16.h>

// Problem constants (fixed by reference)
#define BB 8
#define NN 1024
#define HH 768
#define NHEAD 12
#define HD 64
#define NSEG 8192            // B*N
#define QKVN 2304            // 3*H
#define MAXDEG 64            // bucket capacity per segment (Poisson(16); P(>64) ~ 1e-18)

typedef unsigned short u16;
typedef __attribute__((ext_vector_type(8))) _Float16 f16x8;
typedef __attribute__((ext_vector_type(4))) float f32x4;
typedef __attribute__((ext_vector_type(4))) unsigned int u32x4;
typedef __attribute__((ext_vector_type(2))) unsigned int u32x2;

__device__ __forceinline__ u16 f2h(float f) {
  _Float16 h = (_Float16)f;
  return __builtin_bit_cast(u16, h);
}
__device__ __forceinline__ __half2 h2(unsigned int w) {
  return __builtin_bit_cast(__half2, w);
}

// ---------------- fused prep: cast X, transpose W, build CSR ----------------
#define CAST_BLKS (NSEG * HH / 4 / 256)     // 6144
#define TW_BLKS   ((QKVN / 32) * (HH / 32)) // 1728
#define BUILD_BLKS 512

__global__ void prep_kernel(const float* __restrict__ X, u16* __restrict__ Xb,
                            const float* __restrict__ Wq, const float* __restrict__ Wk,
                            const float* __restrict__ Wv, u16* __restrict__ Wt,
                            const int* __restrict__ EI, int* __restrict__ cursor,
                            int* __restrict__ tailrow, int E) {
  const int bid = blockIdx.x;
  if (bid < CAST_BLKS) {
    int i = bid * 256 + threadIdx.x;
    float4 f = ((const float4*)X)[i];
    ushort4 o;
    o.x = f2h(f.x); o.y = f2h(f.y); o.z = f2h(f.z); o.w = f2h(f.w);
    ((ushort4*)Xb)[i] = o;
  } else if (bid < CAST_BLKS + TW_BLKS) {
    __shared__ float tile[32][33];
    int t = bid - CAST_BLKS;
    int n0 = (t % (QKVN / 32)) * 32;
    int k0 = (t / (QKVN / 32)) * 32;
    const float* W = (n0 < HH) ? Wq : (n0 < 2 * HH ? Wk : Wv);
    int nb = n0 - (n0 < HH ? 0 : (n0 < 2 * HH ? HH : 2 * HH));
    int tx = threadIdx.x & 31, ty = threadIdx.x >> 5;   // (32, 8)
#pragma unroll
    for (int r = 0; r < 4; ++r)
      tile[ty + 8 * r][tx] = W[(k0 + ty + 8 * r) * HH + nb + tx];
    __syncthreads();
#pragma unroll
    for (int r = 0; r < 4; ++r)
      Wt[(n0 + ty + 8 * r) * HH + k0 + tx] = f2h(tile[tx][ty + 8 * r]);
  } else {
    int e = (bid - CAST_BLKS - TW_BLKS) * 256 + threadIdx.x;
    if (e >= E) return;
    int b = EI[e];
    int seg = b * NN + EI[E + e];
    int j = EI[2 * E + e];
    int pos = atomicAdd(&cursor[seg], 1);
    if (pos < MAXDEG) tailrow[seg * MAXDEG + pos] = b * NN + j;
  }
}

// ---------------- fused QKV GEMM: (8192x768) @ (768x2304), f16 MFMA ----------------
// R12: 8-phase-style restructure (T2+T3+T4+T5 from the catalog):
//   BM=256 x BN=128, BK=64, 512 threads (8 waves, 4M x 2N, 64x64/wave).
//   3-buffer LDS rotation (144 KB), counted vmcnt(6) (6 global_load_lds/tile,
//   2 tiles in flight), 2 phases per K-tile each = {8 ds_read_b128 || 3 stage
//   issues -> barrier -> lgkmcnt(0) -> setprio(1) 16xMFMA setprio(0)}.
//   T2: slot-XOR swizzle s^(row&7) on both tiles (128B rows are 16-way
//   conflicted otherwise); applied via pre-swizzled GLOBAL source + swizzled
//   read, LDS dest stays linear (global_load_lds constraint, rule 21).
#define GBM 256
#define GBN 128
#define GBK 64
#define GNT (HH / GBK)   // 12 K-tiles

__global__ __launch_bounds__(512, 2) void gemm_kernel(const u16* __restrict__ Xb,
                                                      const u16* __restrict__ Wt,
                                                      u16* __restrict__ QKV) {
  __shared__ u16 As[3][GBM * GBK];   // 3 x 32 KB
  __shared__ u16 Bs[3][GBN * GBK];   // 3 x 16 KB
  const int tid = threadIdx.x;
  const int wave = tid >> 6;
  const int lane = tid & 63;
  const int quad = lane >> 4;
  const int l15 = lane & 15;
  const int wr = wave >> 1;          // 0..3 (M)
  const int wc = wave & 1;           // 0..1 (N)

  // XCD-aware bijective swizzle: 576 blocks = 8 XCD chunks x 72; m-major
  // within a chunk so an XCD's A-panels stay L2-resident across the n-sweep.
  const int bid = blockIdx.x;
  const int wgid = (bid & 7) * 72 + (bid >> 3);
  const int mt = wgid / 18;          // 0..31
  const int nt = wgid % 18;          // 0..17
  const int m0 = mt * GBM;
  const int n0 = nt * GBN;

  f32x4 acc[4][4] = {};

  // stage half h (h=0,1) of K-tile kt into buffer buf: 2 A-issues + 1 B-issue
  // per thread (3 global_load_lds). LDS dest linear; global source swizzled.
  auto stage_half = [&](int buf, int kt, int h) {
#pragma unroll
    for (int iss = 0; iss < 2; ++iss) {
      const int c = (wave * 4 + h * 2 + iss) * 64 + lane;   // 0..2047
      const int m = c >> 3;
      const u16* ga = Xb + (m0 + m) * HH + kt + (((c & 7) ^ (m & 7)) << 3);
      u16* la = &As[buf][c * 8];
      __builtin_amdgcn_global_load_lds(
          (const __attribute__((address_space(1))) unsigned int*)(unsigned long long)ga,
          (__attribute__((address_space(3))) unsigned int*)(unsigned long long)la, 16, 0, 0);
    }
    {
      const int c = (wave * 2 + h) * 64 + lane;             // 0..1023
      const int n = c >> 3;
      const u16* gb = Wt + (n0 + n) * HH + kt + (((c & 7) ^ (n & 7)) << 3);
      u16* lb = &Bs[buf][c * 8];
      __builtin_amdgcn_global_load_lds(
          (const __attribute__((address_space(1))) unsigned int*)(unsigned long long)gb,
          (__attribute__((address_space(3))) unsigned int*)(unsigned long long)lb, 16, 0, 0);
    }
  };

  // prologue: tiles 0 and 1 in flight (12 outstanding loads/thread)
  stage_half(0, 0, 0);
  stage_half(0, 0, 1);
  stage_half(1, GBK, 0);
  stage_half(1, GBK, 1);

#pragma unroll 3
  for (int it = 0; it < GNT; ++it) {
    // in-order vmcnt retirement: 12 outstanding -> wait to 6 == tile it done
    if (it != GNT - 1) {
      asm volatile("s_waitcnt vmcnt(6)" ::: "memory");
    } else {
      asm volatile("s_waitcnt vmcnt(0)" ::: "memory");
    }
    __builtin_amdgcn_s_barrier();   // tile it visible; tile it-1 fully consumed
    const int b = it % 3;
    const int nb2 = (it + 2) % 3;
    const bool pre = (it + 2) < GNT;
    const int ktn = (it + 2) * GBK;

#pragma unroll
    for (int ks = 0; ks < 2; ++ks) {
      f16x8 afr[4], bfr[4];
#pragma unroll
      for (int mi = 0; mi < 4; ++mi) {
        const int m = wr * 64 + mi * 16 + l15;
        afr[mi] = *(const f16x8*)(&As[b][m * GBK + ((((ks << 2) | quad) ^ (m & 7)) << 3)]);
      }
#pragma unroll
      for (int ni = 0; ni < 4; ++ni) {
        const int n = wc * 64 + ni * 16 + l15;
        bfr[ni] = *(const f16x8*)(&Bs[b][n * GBK + ((((ks << 2) | quad) ^ (n & 7)) << 3)]);
      }
      if (pre) stage_half(nb2, ktn, ks);   // loads stay in flight across barriers
      __builtin_amdgcn_s_barrier();
      asm volatile("s_waitcnt lgkmcnt(0)" ::: "memory");
      __builtin_amdgcn_sched_barrier(0);
      __builtin_amdgcn_s_setprio(1);
#pragma unroll
      for (int mi = 0; mi < 4; ++mi)
#pragma unroll
        for (int ni = 0; ni < 4; ++ni)
          acc[mi][ni] = __builtin_amdgcn_mfma_f32_16x16x32_f16(afr[mi], bfr[ni], acc[mi][ni], 0, 0, 0);
      __builtin_amdgcn_s_setprio(0);
      if (ks == 0) __builtin_amdgcn_s_barrier();
      // ks==1: next iteration's top vmcnt+barrier closes the tile
    }
  }

  // epilogue: C/D layout col=lane&15, row=(lane>>4)*4+reg  [m89-verified]
#pragma unroll
  for (int mi = 0; mi < 4; ++mi)
#pragma unroll
    for (int ni = 0; ni < 4; ++ni) {
      const int col = n0 + wc * 64 + ni * 16 + l15;
#pragma unroll
      for (int r = 0; r < 4; ++r) {
        const int row = m0 + wr * 64 + mi * 16 + quad * 4 + r;
        QKV[row * QKVN + col] = f2h(acc[mi][ni][r]);
      }
    }
}

// ---------------- attention: FOUR waves per segment, LDS merge ----------------
// (unchanged from R11)
__global__ __launch_bounds__(256) void attn_kernel(const u16* __restrict__ QKV,
                                                   const int* __restrict__ tailrow,
                                                   const int* __restrict__ cursor,
                                                   float* __restrict__ out) {
  __shared__ float sm[3 * 16 * 64];   // 12 KB: partial states from waves 1..3
  const int wv = threadIdx.x >> 6;    // 0..3 = edge-stripe
  const int lane = threadIdx.x & 63;
  const int seg = (blockIdx.x & 7) * (NSEG / 8) + (blockIdx.x >> 3);  // XCD affinity
  const int base = seg * MAXDEG;
  int cnt = cursor[seg];
  if (cnt > MAXDEG) cnt = MAXDEG;
  const int myn = (cnt > wv) ? ((cnt - wv + 3) >> 2) : 0;   // edges at wv, wv+4, ...

  int myidx = (lane < cnt) ? tailrow[base + lane] : 0;

  const u16* qrow = QKV + seg * QKVN;
  __half2 q1[4], q2[2];
  {
    u32x4 qa = *(const u32x4*)(qrow + lane * 8);
    u32x2 qb = *(const u32x2*)(qrow + 512 + lane * 4);
    const __half2 sc = __float2half2_rn(0.125f);
#pragma unroll
    for (int i = 0; i < 4; ++i) q1[i] = __hmul2(h2(qa[i]), sc);
    q2[0] = __hmul2(h2(qb[0]), sc);
    q2[1] = __hmul2(h2(qb[1]), sc);
  }

  float m1 = -__builtin_inff(), l1 = 0.f;
  float m2 = -__builtin_inff(), l2 = 0.f;
  __half2 o1[4] = {}, o2[2] = {};

  auto loadkv = [&](int row, u32x4& k1, u32x2& k2, u32x4& v1, u32x2& v2) {
    const u16* kp = QKV + row * QKVN + HH;
    k1 = *(const u32x4*)(kp + lane * 8);
    k2 = *(const u32x2*)(kp + 512 + lane * 4);
    v1 = *(const u32x4*)(kp + HH + lane * 8);
    v2 = *(const u32x2*)(kp + HH + 512 + lane * 4);
  };

  auto process = [&](u32x4 k1, u32x2 k2, u32x4 v1, u32x2 v2) {
    __half2 a1 = __hmul2(q1[0], h2(k1[0]));
    a1 = __hfma2(q1[1], h2(k1[1]), a1);
    a1 = __hfma2(q1[2], h2(k1[2]), a1);
    a1 = __hfma2(q1[3], h2(k1[3]), a1);
    float s1 = __low2float(a1) + __high2float(a1);
    s1 += __shfl_xor(s1, 1, 64);
    s1 += __shfl_xor(s1, 2, 64);
    s1 += __shfl_xor(s1, 4, 64);
    __half2 a2 = __hmul2(q2[0], h2(k2[0]));
    a2 = __hfma2(q2[1], h2(k2[1]), a2);
    float s2 = __low2float(a2) + __high2float(a2);
    s2 += __shfl_xor(s2, 1, 64);
    s2 += __shfl_xor(s2, 2, 64);
    s2 += __shfl_xor(s2, 4, 64);
    s2 += __shfl_xor(s2, 8, 64);
    {
      float mn = fmaxf(m1, s1);
      float al = __expf(m1 - mn);
      float ex = __expf(s1 - mn);
      l1 = l1 * al + ex;
      __half2 ah = __float2half2_rn(al), eh = __float2half2_rn(ex);
#pragma unroll
      for (int i = 0; i < 4; ++i)
        o1[i] = __hfma2(o1[i], ah, __hmul2(h2(v1[i]), eh));
      m1 = mn;
    }
    {
      float mn = fmaxf(m2, s2);
      float al = __expf(m2 - mn);
      float ex = __expf(s2 - mn);
      l2 = l2 * al + ex;
      __half2 ah = __float2half2_rn(al), eh = __float2half2_rn(ex);
      o2[0] = __hfma2(o2[0], ah, __hmul2(h2(v2[0]), eh));
      o2[1] = __hfma2(o2[1], ah, __hmul2(h2(v2[1]), eh));
      m2 = mn;
    }
  };

  if (myn > 0) {
    u32x4 k1c, v1c, k1n, v1n, k1n2, v1n2;
    u32x2 k2c, v2c, k2n, v2n, k2n2, v2n2;
    loadkv(__shfl(myidx, wv, 64), k1c, k2c, v1c, v2c);
    if (myn > 1) loadkv(__shfl(myidx, wv + 4, 64), k1n, k2n, v1n, v2n);
    for (int t = 0; t < myn; ++t) {
      if (t + 2 < myn)
        loadkv(__shfl(myidx, wv + 4 * (t + 2), 64), k1n2, k2n2, v1n2, v2n2);
      process(k1c, k2c, v1c, v2c);
      k1c = k1n; k2c = k2n; v1c = v1n; v2c = v2n;
      k1n = k1n2; k2n = k2n2; v1n = v1n2; v2n = v2n2;
    }
  }

  float of1[8], of2[4];
#pragma unroll
  for (int i = 0; i < 4; ++i) {
    of1[2 * i] = __low2float(o1[i]);
    of1[2 * i + 1] = __high2float(o1[i]);
  }
#pragma unroll
  for (int i = 0; i < 2; ++i) {
    of2[2 * i] = __low2float(o2[i]);
    of2[2 * i + 1] = __high2float(o2[i]);
  }

  if (wv > 0) {
    float* sb = sm + (wv - 1) * 1024;
    sb[0 * 64 + lane] = m1;  sb[1 * 64 + lane] = l1;
    sb[2 * 64 + lane] = m2;  sb[3 * 64 + lane] = l2;
#pragma unroll
    for (int i = 0; i < 8; ++i) sb[(4 + i) * 64 + lane] = of1[i];
#pragma unroll
    for (int i = 0; i < 4; ++i) sb[(12 + i) * 64 + lane] = of2[i];
  }
  __syncthreads();
  if (wv == 0) {
    float mn1 = fmaxf(m1, -1e30f), mn2 = fmaxf(m2, -1e30f);
#pragma unroll
    for (int j = 0; j < 3; ++j) {
      mn1 = fmaxf(mn1, sm[j * 1024 + 0 * 64 + lane]);
      mn2 = fmaxf(mn2, sm[j * 1024 + 2 * 64 + lane]);
    }
    float res1[8], res2[4];
    {
      float a0 = __expf(m1 - mn1);
      float l = l1 * a0;
#pragma unroll
      for (int i = 0; i < 8; ++i) res1[i] = of1[i] * a0;
#pragma unroll
      for (int j = 0; j < 3; ++j) {
        const float* sb = sm + j * 1024;
        float aj = __expf(sb[0 * 64 + lane] - mn1);
        l += sb[1 * 64 + lane] * aj;
#pragma unroll
        for (int i = 0; i < 8; ++i) res1[i] += sb[(4 + i) * 64 + lane] * aj;
      }
      float inv = 1.f / fmaxf(l, 1e-9f);
#pragma unroll
      for (int i = 0; i < 8; ++i) res1[i] *= inv;
    }
    {
      float a0 = __expf(m2 - mn2);
      float l = l2 * a0;
#pragma unroll
      for (int i = 0; i < 4; ++i) res2[i] = of2[i] * a0;
#pragma unroll
      for (int j = 0; j < 3; ++j) {
        const float* sb = sm + j * 1024;
        float aj = __expf(sb[2 * 64 + lane] - mn2);
        l += sb[3 * 64 + lane] * aj;
#pragma unroll
        for (int i = 0; i < 4; ++i) res2[i] += sb[(12 + i) * 64 + lane] * aj;
      }
      float inv = 1.f / fmaxf(l, 1e-9f);
#pragma unroll
      for (int i = 0; i < 4; ++i) res2[i] *= inv;
    }

    float* op = out + seg * HH;
    float4 r0 = {res1[0], res1[1], res1[2], res1[3]};
    float4 r1 = {res1[4], res1[5], res1[6], res1[7]};
    float4 r2 = {res2[0], res2[1], res2[2], res2[3]};
    ((float4*)(op + lane * 8))[0] = r0;
    ((float4*)(op + lane * 8))[1] = r1;
    *(float4*)(op + 512 + lane * 4) = r2;
  }
}

// ---------------- launch ----------------
extern "C" void kernel_launch(void* const* d_in, const int* in_sizes, int n_in,
                              void* d_out, int out_size, void* d_ws, size_t ws_size,
                              hipStream_t stream) {
  const float* X  = (const float*)d_in[0];
  const int*   EI = (const int*)d_in[1];
  const float* Wq = (const float*)d_in[2];
  const float* Wk = (const float*)d_in[3];
  const float* Wv = (const float*)d_in[4];
  float* out = (float*)d_out;
  const int E = in_sizes[1] / 4;

  // workspace layout (~56 MB)
  char* ws = (char*)d_ws;
  int* cursor  = (int*)(ws);                 // 32 KB
  int* tailrow = (int*)(ws + 32768);         // NSEG*64*4 = 2 MB
  u16* Xb      = (u16*)(ws + 2129920);       // 8192*768*2  = 12.6 MB  (f16)
  u16* Wt      = (u16*)(ws + 14712832);      // 2304*768*2  = 3.5 MB   (f16)
  u16* QKV     = (u16*)(ws + 18251776);      // 8192*2304*2 = 37.7 MB  (f16)

  hipMemsetAsync(cursor, 0, NSEG * 4, stream);
  prep_kernel<<<CAST_BLKS + TW_BLKS + BUILD_BLKS, 256, 0, stream>>>(
      X, Xb, Wq, Wk, Wv, Wt, EI, cursor, tailrow, E);
  gemm_kernel<<<(NSEG / GBM) * (QKVN / GBN), 512, 0, stream>>>(Xb, Wt, QKV);
  attn_kernel<<<NSEG, 256, 0, stream>>>(QKV, tailrow, cursor, out);
}

// Round 2
// 165.819 us; speedup vs baseline: 1.0698x; 1.0698x over previous
//
#include <hip/hip_runtime.h>
#include <hip/hip_fp16.h>

// Problem constants (fixed by reference)
#define BB 8
#define NN 1024
#define HH 768
#define NHEAD 12
#define HD 64
#define NSEG 8192            // B*N
#define QKVN 2304            // 3*H
#define MAXDEG 64            // bucket capacity per segment (Poisson(16); P(>64) ~ 1e-18)

typedef unsigned short u16;
typedef __attribute__((ext_vector_type(8))) _Float16 f16x8;
typedef __attribute__((ext_vector_type(4))) float f32x4;
typedef __attribute__((ext_vector_type(4))) unsigned int u32x4;
typedef __attribute__((ext_vector_type(2))) unsigned int u32x2;

__device__ __forceinline__ u16 f2h(float f) {
  _Float16 h = (_Float16)f;
  return __builtin_bit_cast(u16, h);
}
__device__ __forceinline__ __half2 h2(unsigned int w) {
  return __builtin_bit_cast(__half2, w);
}

// ---------------- fused prep: cast X, transpose W, build CSR ----------------
#define CAST_BLKS (NSEG * HH / 4 / 256)     // 6144
#define TW_BLKS   ((QKVN / 32) * (HH / 32)) // 1728
#define BUILD_BLKS 512

__global__ void prep_kernel(const float* __restrict__ X, u16* __restrict__ Xb,
                            const float* __restrict__ Wq, const float* __restrict__ Wk,
                            const float* __restrict__ Wv, u16* __restrict__ Wt,
                            const int* __restrict__ EI, int* __restrict__ cursor,
                            int* __restrict__ tailrow, int E) {
  const int bid = blockIdx.x;
  if (bid < CAST_BLKS) {
    int i = bid * 256 + threadIdx.x;
    float4 f = ((const float4*)X)[i];
    ushort4 o;
    o.x = f2h(f.x); o.y = f2h(f.y); o.z = f2h(f.z); o.w = f2h(f.w);
    ((ushort4*)Xb)[i] = o;
  } else if (bid < CAST_BLKS + TW_BLKS) {
    __shared__ float tile[32][33];
    int t = bid - CAST_BLKS;
    int n0 = (t % (QKVN / 32)) * 32;
    int k0 = (t / (QKVN / 32)) * 32;
    const float* W = (n0 < HH) ? Wq : (n0 < 2 * HH ? Wk : Wv);
    int nb = n0 - (n0 < HH ? 0 : (n0 < 2 * HH ? HH : 2 * HH));
    int tx = threadIdx.x & 31, ty = threadIdx.x >> 5;   // (32, 8)
#pragma unroll
    for (int r = 0; r < 4; ++r)
      tile[ty + 8 * r][tx] = W[(k0 + ty + 8 * r) * HH + nb + tx];
    __syncthreads();
#pragma unroll
    for (int r = 0; r < 4; ++r)
      Wt[(n0 + ty + 8 * r) * HH + k0 + tx] = f2h(tile[tx][ty + 8 * r]);
  } else {
    int e = (bid - CAST_BLKS - TW_BLKS) * 256 + threadIdx.x;
    if (e >= E) return;
    int b = EI[e];
    int seg = b * NN + EI[E + e];
    int j = EI[2 * E + e];
    int pos = atomicAdd(&cursor[seg], 1);
    if (pos < MAXDEG) tailrow[seg * MAXDEG + pos] = b * NN + j;
  }
}

// ---------------- fused QKV GEMM: (8192x768) @ (768x2304), f16 MFMA ----------------
// R13: 2-resident-block restructure.
//   BM=256 x BN=128, 256 threads = 4 waves, wave-tile 128x64 (2M x 2N waves).
//   Wave-tile 128x64 gives 42.7 MFMA-FLOP per LDS-byte (64x64 was 32 = exactly
//   the LDS BW balance point -> LDS-bound). BK=32, 3-buffer rotation = 72 KB
//   LDS -> 2 blocks/CU co-resident (8 waves/CU): tail round absorbed, and the
//   other block's waves fill this block's barrier drains.
//   Counted vmcnt(6): 6 global_load_lds per tile per thread, 2 tiles in
//   flight, never drained to 0 in the loop (T4). T2 slot-XOR swizzle
//   (slot ^= row&3, 4 slots/row at BK=32; max 2-way conflict = free).
//   T5 setprio around each 16-MFMA cluster.
#define GBM 256
#define GBN 128
#define GBK 32
#define GNT (HH / GBK)   // 24 K-tiles

__global__ __launch_bounds__(256, 2) void gemm_kernel(const u16* __restrict__ Xb,
                                                      const u16* __restrict__ Wt,
                                                      u16* __restrict__ QKV) {
  __shared__ u16 As[3][GBM * GBK];   // 3 x 16 KB
  __shared__ u16 Bs[3][GBN * GBK];   // 3 x 8 KB
  const int tid = threadIdx.x;
  const int wave = tid >> 6;
  const int lane = tid & 63;
  const int quad = lane >> 4;
  const int l15 = lane & 15;
  const int wm = (wave >> 1) * 128;  // wave M-offset within block
  const int wn = (wave & 1) * 64;    // wave N-offset within block

  // XCD-aware bijective swizzle: 576 blocks = 8 chunks x 72; m-major within a
  // chunk so an XCD's A-panels stay L2-resident across its n-sweep.
  const int bid = blockIdx.x;
  const int wgid = (bid & 7) * 72 + (bid >> 3);
  const int mt = wgid / 18;          // 0..31
  const int nt = wgid % 18;          // 0..17
  const int m0 = mt * GBM;
  const int n0 = nt * GBN;

  f32x4 acc[8][4] = {};

  // stage part p (p=0,1) of K-tile kt into buffer buf: 2 A-issues + 1 B-issue.
  // LDS dest linear (chunk c -> byte c*16); global source pre-swizzled so that
  // stored slot s of row r holds global k-chunk s^(r&3) (involution).
  auto stage_part = [&](int buf, int kt, int p) {
#pragma unroll
    for (int iss = 0; iss < 2; ++iss) {
      const int c = (p * 2 + iss) * 256 + tid;   // 0..1023 (A: 1024 chunks)
      const int r = c >> 2;
      const u16* ga = Xb + (m0 + r) * HH + kt + (((c & 3) ^ (r & 3)) << 3);
      u16* la = &As[buf][c * 8];
      __builtin_amdgcn_global_load_lds(
          (const __attribute__((address_space(1))) unsigned int*)(unsigned long long)ga,
          (__attribute__((address_space(3))) unsigned int*)(unsigned long long)la, 16, 0, 0);
    }
    {
      const int c = p * 256 + tid;               // 0..511 (B: 512 chunks)
      const int r = c >> 2;
      const u16* gb = Wt + (n0 + r) * HH + kt + (((c & 3) ^ (r & 3)) << 3);
      u16* lb = &Bs[buf][c * 8];
      __builtin_amdgcn_global_load_lds(
          (const __attribute__((address_space(1))) unsigned int*)(unsigned long long)gb,
          (__attribute__((address_space(3))) unsigned int*)(unsigned long long)lb, 16, 0, 0);
    }
  };

  // prologue: tiles 0 and 1 in flight (12 outstanding loads/thread)
  stage_part(0, 0, 0);
  stage_part(0, 0, 1);
  stage_part(1, GBK, 0);
  stage_part(1, GBK, 1);

#pragma unroll 3
  for (int it = 0; it < GNT; ++it) {
    // in-order vmcnt retirement: up to 12 outstanding -> wait to 6 == tile it done
    if (it != GNT - 1) {
      asm volatile("s_waitcnt vmcnt(6)" ::: "memory");
    } else {
      asm volatile("s_waitcnt vmcnt(0)" ::: "memory");
    }
    __builtin_amdgcn_s_barrier();   // tile it visible; tile it-1 fully consumed
    const int b = it % 3;
    const int nb2 = (it + 2) % 3;
    const bool pre = (it + 2) < GNT;
    const int ktn = (it + 2) * GBK;

    f16x8 bfr[4];
#pragma unroll
    for (int s = 0; s < 2; ++s) {
      f16x8 afr[4];
#pragma unroll
      for (int mi = 0; mi < 4; ++mi) {
        const int m = wm + (s * 4 + mi) * 16 + l15;
        afr[mi] = *(const f16x8*)(&As[b][m * GBK + ((quad ^ (m & 3)) << 3)]);
      }
      if (s == 0) {
#pragma unroll
        for (int ni = 0; ni < 4; ++ni) {
          const int n = wn + ni * 16 + l15;
          bfr[ni] = *(const f16x8*)(&Bs[b][n * GBK + ((quad ^ (n & 3)) << 3)]);
        }
      }
      if (pre) stage_part(nb2, ktn, s);   // loads stay in flight across barriers
      __builtin_amdgcn_s_barrier();
      asm volatile("s_waitcnt lgkmcnt(0)" ::: "memory");
      __builtin_amdgcn_sched_barrier(0);
      __builtin_amdgcn_s_setprio(1);
#pragma unroll
      for (int mi = 0; mi < 4; ++mi)
#pragma unroll
        for (int ni = 0; ni < 4; ++ni)
          acc[s * 4 + mi][ni] = __builtin_amdgcn_mfma_f32_16x16x32_f16(afr[mi], bfr[ni], acc[s * 4 + mi][ni], 0, 0, 0);
      __builtin_amdgcn_s_setprio(0);
      // s==1: next iteration's top vmcnt+barrier closes the tile
    }
  }

  // epilogue: C/D layout col=lane&15, row=(lane>>4)*4+reg  [m89-verified]
#pragma unroll
  for (int mi = 0; mi < 8; ++mi)
#pragma unroll
    for (int ni = 0; ni < 4; ++ni) {
      const int col = n0 + wn + ni * 16 + l15;
#pragma unroll
      for (int r = 0; r < 4; ++r) {
        const int row = m0 + wm + mi * 16 + quad * 4 + r;
        QKV[row * QKVN + col] = f2h(acc[mi][ni][r]);
      }
    }
}

// ---------------- attention: FOUR waves per segment, LDS merge ----------------
// (unchanged)
__global__ __launch_bounds__(256) void attn_kernel(const u16* __restrict__ QKV,
                                                   const int* __restrict__ tailrow,
                                                   const int* __restrict__ cursor,
                                                   float* __restrict__ out) {
  __shared__ float sm[3 * 16 * 64];   // 12 KB: partial states from waves 1..3
  const int wv = threadIdx.x >> 6;    // 0..3 = edge-stripe
  const int lane = threadIdx.x & 63;
  const int seg = (blockIdx.x & 7) * (NSEG / 8) + (blockIdx.x >> 3);  // XCD affinity
  const int base = seg * MAXDEG;
  int cnt = cursor[seg];
  if (cnt > MAXDEG) cnt = MAXDEG;
  const int myn = (cnt > wv) ? ((cnt - wv + 3) >> 2) : 0;   // edges at wv, wv+4, ...

  int myidx = (lane < cnt) ? tailrow[base + lane] : 0;

  const u16* qrow = QKV + seg * QKVN;
  __half2 q1[4], q2[2];
  {
    u32x4 qa = *(const u32x4*)(qrow + lane * 8);
    u32x2 qb = *(const u32x2*)(qrow + 512 + lane * 4);
    const __half2 sc = __float2half2_rn(0.125f);
#pragma unroll
    for (int i = 0; i < 4; ++i) q1[i] = __hmul2(h2(qa[i]), sc);
    q2[0] = __hmul2(h2(qb[0]), sc);
    q2[1] = __hmul2(h2(qb[1]), sc);
  }

  float m1 = -__builtin_inff(), l1 = 0.f;
  float m2 = -__builtin_inff(), l2 = 0.f;
  __half2 o1[4] = {}, o2[2] = {};

  auto loadkv = [&](int row, u32x4& k1, u32x2& k2, u32x4& v1, u32x2& v2) {
    const u16* kp = QKV + row * QKVN + HH;
    k1 = *(const u32x4*)(kp + lane * 8);
    k2 = *(const u32x2*)(kp + 512 + lane * 4);
    v1 = *(const u32x4*)(kp + HH + lane * 8);
    v2 = *(const u32x2*)(kp + HH + 512 + lane * 4);
  };

  auto process = [&](u32x4 k1, u32x2 k2, u32x4 v1, u32x2 v2) {
    __half2 a1 = __hmul2(q1[0], h2(k1[0]));
    a1 = __hfma2(q1[1], h2(k1[1]), a1);
    a1 = __hfma2(q1[2], h2(k1[2]), a1);
    a1 = __hfma2(q1[3], h2(k1[3]), a1);
    float s1 = __low2float(a1) + __high2float(a1);
    s1 += __shfl_xor(s1, 1, 64);
    s1 += __shfl_xor(s1, 2, 64);
    s1 += __shfl_xor(s1, 4, 64);
    __half2 a2 = __hmul2(q2[0], h2(k2[0]));
    a2 = __hfma2(q2[1], h2(k2[1]), a2);
    float s2 = __low2float(a2) + __high2float(a2);
    s2 += __shfl_xor(s2, 1, 64);
    s2 += __shfl_xor(s2, 2, 64);
    s2 += __shfl_xor(s2, 4, 64);
    s2 += __shfl_xor(s2, 8, 64);
    {
      float mn = fmaxf(m1, s1);
      float al = __expf(m1 - mn);
      float ex = __expf(s1 - mn);
      l1 = l1 * al + ex;
      __half2 ah = __float2half2_rn(al), eh = __float2half2_rn(ex);
#pragma unroll
      for (int i = 0; i < 4; ++i)
        o1[i] = __hfma2(o1[i], ah, __hmul2(h2(v1[i]), eh));
      m1 = mn;
    }
    {
      float mn = fmaxf(m2, s2);
      float al = __expf(m2 - mn);
      float ex = __expf(s2 - mn);
      l2 = l2 * al + ex;
      __half2 ah = __float2half2_rn(al), eh = __float2half2_rn(ex);
      o2[0] = __hfma2(o2[0], ah, __hmul2(h2(v2[0]), eh));
      o2[1] = __hfma2(o2[1], ah, __hmul2(h2(v2[1]), eh));
      m2 = mn;
    }
  };

  if (myn > 0) {
    u32x4 k1c, v1c, k1n, v1n, k1n2, v1n2;
    u32x2 k2c, v2c, k2n, v2n, k2n2, v2n2;
    loadkv(__shfl(myidx, wv, 64), k1c, k2c, v1c, v2c);
    if (myn > 1) loadkv(__shfl(myidx, wv + 4, 64), k1n, k2n, v1n, v2n);
    for (int t = 0; t < myn; ++t) {
      if (t + 2 < myn)
        loadkv(__shfl(myidx, wv + 4 * (t + 2), 64), k1n2, k2n2, v1n2, v2n2);
      process(k1c, k2c, v1c, v2c);
      k1c = k1n; k2c = k2n; v1c = v1n; v2c = v2n;
      k1n = k1n2; k2n = k2n2; v1n = v1n2; v2n = v2n2;
    }
  }

  float of1[8], of2[4];
#pragma unroll
  for (int i = 0; i < 4; ++i) {
    of1[2 * i] = __low2float(o1[i]);
    of1[2 * i + 1] = __high2float(o1[i]);
  }
#pragma unroll
  for (int i = 0; i < 2; ++i) {
    of2[2 * i] = __low2float(o2[i]);
    of2[2 * i + 1] = __high2float(o2[i]);
  }

  if (wv > 0) {
    float* sb = sm + (wv - 1) * 1024;
    sb[0 * 64 + lane] = m1;  sb[1 * 64 + lane] = l1;
    sb[2 * 64 + lane] = m2;  sb[3 * 64 + lane] = l2;
#pragma unroll
    for (int i = 0; i < 8; ++i) sb[(4 + i) * 64 + lane] = of1[i];
#pragma unroll
    for (int i = 0; i < 4; ++i) sb[(12 + i) * 64 + lane] = of2[i];
  }
  __syncthreads();
  if (wv == 0) {
    float mn1 = fmaxf(m1, -1e30f), mn2 = fmaxf(m2, -1e30f);
#pragma unroll
    for (int j = 0; j < 3; ++j) {
      mn1 = fmaxf(mn1, sm[j * 1024 + 0 * 64 + lane]);
      mn2 = fmaxf(mn2, sm[j * 1024 + 2 * 64 + lane]);
    }
    float res1[8], res2[4];
    {
      float a0 = __expf(m1 - mn1);
      float l = l1 * a0;
#pragma unroll
      for (int i = 0; i < 8; ++i) res1[i] = of1[i] * a0;
#pragma unroll
      for (int j = 0; j < 3; ++j) {
        const float* sb = sm + j * 1024;
        float aj = __expf(sb[0 * 64 + lane] - mn1);
        l += sb[1 * 64 + lane] * aj;
#pragma unroll
        for (int i = 0; i < 8; ++i) res1[i] += sb[(4 + i) * 64 + lane] * aj;
      }
      float inv = 1.f / fmaxf(l, 1e-9f);
#pragma unroll
      for (int i = 0; i < 8; ++i) res1[i] *= inv;
    }
    {
      float a0 = __expf(m2 - mn2);
      float l = l2 * a0;
#pragma unroll
      for (int i = 0; i < 4; ++i) res2[i] = of2[i] * a0;
#pragma unroll
      for (int j = 0; j < 3; ++j) {
        const float* sb = sm + j * 1024;
        float aj = __expf(sb[2 * 64 + lane] - mn2);
        l += sb[3 * 64 + lane] * aj;
#pragma unroll
        for (int i = 0; i < 4; ++i) res2[i] += sb[(12 + i) * 64 + lane] * aj;
      }
      float inv = 1.f / fmaxf(l, 1e-9f);
#pragma unroll
      for (int i = 0; i < 4; ++i) res2[i] *= inv;
    }

    float* op = out + seg * HH;
    float4 r0 = {res1[0], res1[1], res1[2], res1[3]};
    float4 r1 = {res1[4], res1[5], res1[6], res1[7]};
    float4 r2 = {res2[0], res2[1], res2[2], res2[3]};
    ((float4*)(op + lane * 8))[0] = r0;
    ((float4*)(op + lane * 8))[1] = r1;
    *(float4*)(op + 512 + lane * 4) = r2;
  }
}

// ---------------- launch ----------------
extern "C" void kernel_launch(void* const* d_in, const int* in_sizes, int n_in,
                              void* d_out, int out_size, void* d_ws, size_t ws_size,
                              hipStream_t stream) {
  const float* X  = (const float*)d_in[0];
  const int*   EI = (const int*)d_in[1];
  const float* Wq = (const float*)d_in[2];
  const float* Wk = (const float*)d_in[3];
  const float* Wv = (const float*)d_in[4];
  float* out = (float*)d_out;
  const int E = in_sizes[1] / 4;

  // workspace layout (~56 MB)
  char* ws = (char*)d_ws;
  int* cursor  = (int*)(ws);                 // 32 KB
  int* tailrow = (int*)(ws + 32768);         // NSEG*64*4 = 2 MB
  u16* Xb      = (u16*)(ws + 2129920);       // 8192*768*2  = 12.6 MB  (f16)
  u16* Wt      = (u16*)(ws + 14712832);      // 2304*768*2  = 3.5 MB   (f16)
  u16* QKV     = (u16*)(ws + 18251776);      // 8192*2304*2 = 37.7 MB  (f16)

  hipMemsetAsync(cursor, 0, NSEG * 4, stream);
  prep_kernel<<<CAST_BLKS + TW_BLKS + BUILD_BLKS, 256, 0, stream>>>(
      X, Xb, Wq, Wk, Wv, Wt, EI, cursor, tailrow, E);
  gemm_kernel<<<(NSEG / GBM) * (QKVN / GBN), 256, 0, stream>>>(Xb, Wt, QKV);
  attn_kernel<<<NSEG, 256, 0, stream>>>(QKV, tailrow, cursor, out);
}